// Round 1
// baseline (2982.298 us; speedup 1.0000x reference)
//
#include <hip/hip_runtime.h>
#include <stdint.h>
#include <stddef.h>

// LSTM: B=512, T=128, D=256, H=256, C=128, gates (i,j,f,o), FORGET_BIAS=1.0
// 32 persistent blocks x 1024 threads; each block owns 16 batch rows end-to-end.
// Fused kernel W[512,1024] held bf16 in registers as MFMA B-fragments
// (256 VGPR/wave). No inter-block sync; c-state stays fp32 in registers.

#define TT   128
#define DD   256
#define HH   256
#define KDIM 512
#define LDA  520   // bf16 elems per A-tile row: 512 + 8 pad (16B) -> 2-way LDS conflict (free)

typedef __attribute__((ext_vector_type(8))) __bf16 bf16x8;
typedef __attribute__((ext_vector_type(4))) __bf16 bf16x4;
typedef __attribute__((ext_vector_type(4))) float  f32x4;

__device__ __forceinline__ f32x4 mfma16(bf16x8 a, bf16x8 b, f32x4 c) {
    return __builtin_amdgcn_mfma_f32_16x16x32_bf16(a, b, c, 0, 0, 0);
}

__device__ __forceinline__ float sigmoidf_(float v) {
    return 1.0f / (1.0f + __expf(-v));
}
__device__ __forceinline__ float tanhf_(float v) {
    float e = __expf(-2.0f * fabsf(v));
    float t = (1.0f - e) / (1.0f + e);
    return copysignf(t, v);
}

__global__ __launch_bounds__(1024) void lstm_persistent(
    const float* __restrict__ x,     // [512,128,256]
    const float* __restrict__ Wk,    // [512,1024]
    const float* __restrict__ bias,  // [1024]
    const float* __restrict__ wout,  // [256,128]
    const float* __restrict__ bout,  // [128]
    float* __restrict__ out)         // [512,128]
{
    __shared__ __attribute__((aligned(16))) __bf16 Atile[16 * LDA];

    const int tid  = threadIdx.x;
    const int wv   = tid >> 6;     // wave 0..15
    const int lane = tid & 63;
    const int l16  = lane & 15;
    const int quad = lane >> 4;    // 0..3
    const int rowbase = blockIdx.x << 4;
    const int gcol = wv * 16 + l16;   // this wave's h/z column (per gate)

    // ---- one-time: load W[512,1024] -> bf16 B-fragments in registers ----
    // B-frag layout (16x16x32): lane holds B[k = 32*kt + quad*8 + j][n = l16]
    bf16x8 wfrag[4][16];
#pragma unroll
    for (int g = 0; g < 4; ++g) {
#pragma unroll
        for (int kt = 0; kt < 16; ++kt) {
            bf16x8 f;
#pragma unroll
            for (int j = 0; j < 8; ++j) {
                int r = kt * 32 + quad * 8 + j;
                f[j] = (__bf16)Wk[r * 1024 + g * 256 + gcol];
            }
            wfrag[g][kt] = f;
        }
    }
    const float bI = bias[0 * 256 + gcol];
    const float bJ = bias[1 * 256 + gcol];
    const float bF = bias[2 * 256 + gcol] + 1.0f;  // FORGET_BIAS folded in
    const float bO = bias[3 * 256 + gcol];

    float c_[4] = {0.f, 0.f, 0.f, 0.f};
    float h_[4] = {0.f, 0.f, 0.f, 0.f};

#pragma unroll 1
    for (int t = 0; t < TT; ++t) {
        __syncthreads();  // prior iteration's A-tile reads complete (WAR)

        // stage x_t: wave wv loads batch row wv, 4 floats/lane (coalesced 1KB/row)
        {
            const float4 xv = *((const float4*)(x + ((size_t)(rowbase + wv) * TT + t) * DD) + lane);
            bf16x4 xb = { (__bf16)xv.x, (__bf16)xv.y, (__bf16)xv.z, (__bf16)xv.w };
            *(bf16x4*)&Atile[wv * LDA + lane * 4] = xb;
        }
        // stage h_t (bf16) from this wave's C-layout registers: rows quad*4+r, col 256+gcol
#pragma unroll
        for (int r = 0; r < 4; ++r)
            Atile[(quad * 4 + r) * LDA + 256 + gcol] = (__bf16)h_[r];

        __syncthreads();  // A-tile ready

        // z[16 rows, 4 gates x 16 cols] = A[16,512] @ W  (K fused: x-part + h-part)
        f32x4 a0 = {0,0,0,0}, a1 = {0,0,0,0}, a2 = {0,0,0,0}, a3 = {0,0,0,0};
#pragma unroll
        for (int kt = 0; kt < 16; ++kt) {
            // A-frag: lane holds A[m = l16][k = 32*kt + quad*8 + j]
            bf16x8 af = *(const bf16x8*)&Atile[l16 * LDA + kt * 32 + quad * 8];
            a0 = mfma16(af, wfrag[0][kt], a0);
            a1 = mfma16(af, wfrag[1][kt], a1);
            a2 = mfma16(af, wfrag[2][kt], a2);
            a3 = mfma16(af, wfrag[3][kt], a3);
        }

        // gate epilogue; C/D layout: col = l16, row = quad*4 + r
#pragma unroll
        for (int r = 0; r < 4; ++r) {
            float iv = a0[r] + bI;
            float jv = a1[r] + bJ;
            float fv = a2[r] + bF;
            float ov = a3[r] + bO;
            float c  = c_[r] * sigmoidf_(fv) + sigmoidf_(iv) * tanhf_(jv);
            c_[r] = c;
            h_[r] = tanhf_(c) * sigmoidf_(ov);
        }
    }

    // ---- output: out[16,128] = h_last[16,256] @ wout + bout, via MFMA ----
    __syncthreads();
#pragma unroll
    for (int r = 0; r < 4; ++r)
        Atile[(quad * 4 + r) * LDA + 256 + gcol] = (__bf16)h_[r];
    __syncthreads();

    if (wv < 8) {  // 8 waves x 16 cols = 128 output cols
        bf16x8 wo[8];
#pragma unroll
        for (int kt = 0; kt < 8; ++kt) {
            bf16x8 f;
#pragma unroll
            for (int j = 0; j < 8; ++j)
                f[j] = (__bf16)wout[(kt * 32 + quad * 8 + j) * 128 + gcol];
            wo[kt] = f;
        }
        f32x4 acc = {0, 0, 0, 0};
#pragma unroll
        for (int kt = 0; kt < 8; ++kt) {
            bf16x8 af = *(const bf16x8*)&Atile[l16 * LDA + 256 + kt * 32 + quad * 8];
            acc = mfma16(af, wo[kt], acc);
        }
        const float bo = bout[gcol];
#pragma unroll
        for (int r = 0; r < 4; ++r)
            out[(size_t)(rowbase + quad * 4 + r) * 128 + gcol] = acc[r] + bo;
    }
}

extern "C" void kernel_launch(void* const* d_in, const int* in_sizes, int n_in,
                              void* d_out, int out_size, void* d_ws, size_t ws_size,
                              hipStream_t stream) {
    const float* x    = (const float*)d_in[0];
    const float* Wk   = (const float*)d_in[1];
    const float* bias = (const float*)d_in[2];
    const float* wout = (const float*)d_in[3];
    const float* bout = (const float*)d_in[4];
    float* out = (float*)d_out;
    hipLaunchKernelGGL(lstm_persistent, dim3(32), dim3(1024), 0, stream,
                       x, Wk, bias, wout, bout, out);
}

// Round 2
// 842.604 us; speedup vs baseline: 3.5394x; 3.5394x over previous
//
#include <hip/hip_runtime.h>
#include <hip/hip_fp16.h>
#include <stdint.h>
#include <stddef.h>

// LSTM B=512,T=128,D=256,H=256,C=128, gates (i,j,f,o), FORGET_BIAS=1.
// 3-kernel pipeline:
//  1) shuffle_w : Wk[512,1024] fp32 -> bf16 MFMA B-frag order (WxF | WhF) in ws
//  2) xproj     : Zx2 = x@Wx + bias (+1 on f-gate), fp16, lane-swizzled layout
//  3) lstm_rec  : 32 persistent blocks x 512 thr; Wh 100% resident (regs+LDS)

typedef __attribute__((ext_vector_type(8))) __bf16 bf16x8;
typedef __attribute__((ext_vector_type(4))) __bf16 bf16x4;
typedef __attribute__((ext_vector_type(4))) float  f32x4;

#define NREGF 46                       // weight frags per wave in registers (184 VGPR)
#define NLDSF 18                       // weight frags per wave in LDS (18 KB/wave... 1KB each)
#define LDH   264                      // Ht row stride in bf16 (256 + 8 pad)
#define FRAG_BYTES (NLDSF * 8 * 64 * 16)        // 147456
#define HT_OFF     FRAG_BYTES
#define SMEM_BYTES (FRAG_BYTES + 16 * LDH * 2)  // 155904 <= 160 KiB

__device__ __forceinline__ f32x4 mfma16(bf16x8 a, bf16x8 b, f32x4 c) {
    return __builtin_amdgcn_mfma_f32_16x16x32_bf16(a, b, c, 0, 0, 0);
}
__device__ __forceinline__ float sig_(float v) { return 1.0f / (1.0f + __expf(-v)); }
__device__ __forceinline__ float th_(float v) {
    float e = __expf(-2.0f * fabsf(v));
    return copysignf((1.0f - e) / (1.0f + e), v);
}

// ---------------- 1) weight shuffle ----------------
// WF layout: part p (0=Wx rows 0..255, 1=Wh rows 256..511), frag id = ntile_glob*8+kt,
// elem: [fid][lane][8 bf16]  (B-frag: lane holds B[k=kt*32+quad*8+j][n=nt*16+l16])
__global__ __launch_bounds__(256) void shuffle_w(const float* __restrict__ Wk,
                                                 __bf16* __restrict__ WF) {
    int id = blockIdx.x * 256 + threadIdx.x;          // 0..65535
    int part = id >> 15;
    int i = id & 32767;
    int lane = i & 63, kt = (i >> 6) & 7, nt = i >> 9;  // nt 0..63
    int quad = lane >> 4, l16 = lane & 15;
    const float* src = Wk + (size_t)(part * 256 + kt * 32 + quad * 8) * 1024 + nt * 16 + l16;
    __bf16* dst = WF + (size_t)part * 262144 + ((size_t)(nt * 8 + kt) * 64 + lane) * 8;
#pragma unroll
    for (int j = 0; j < 8; ++j) dst[j] = (__bf16)src[(size_t)j * 1024];
}

// ---------------- 2) x-projection ----------------
// Zx2 fp16, swizzled: elem(idx) for (rb,t,recurrent-wave wv=nt, lane, idx=wvx*4+r)
// at  ((((rb*128+t)*8 + nt)*64 + lane)*32 + wvx*4 + r)
__global__ __launch_bounds__(512, 2) void xproj(const float* __restrict__ x,
        const __bf16* __restrict__ WxF, const float* __restrict__ bias,
        __half* __restrict__ Zx) {
    __shared__ __attribute__((aligned(16))) __bf16 At[64 * LDH];
    const int tid = threadIdx.x, wv = tid >> 6, lane = tid & 63;
    const int l16 = lane & 15, quad = lane >> 4;
    const int rb = blockIdx.x & 31, tg = blockIdx.x >> 5;

    // stage A: 64 rows = 16 b-rows x 4 t, bf16, coalesced float4 loads
#pragma unroll
    for (int rr = 0; rr < 8; ++rr) {
        int Arow = wv * 8 + rr;
        int tt = Arow >> 4, r = Arow & 15;
        const float4 xv = *((const float4*)(x + ((size_t)(rb * 16 + r) * 128 + tg * 4 + tt) * 256) + lane);
        bf16x4 xb = { (__bf16)xv.x, (__bf16)xv.y, (__bf16)xv.z, (__bf16)xv.w };
        *(bf16x4*)&At[Arow * LDH + lane * 4] = xb;
    }
    __syncthreads();

    f32x4 acc[4][8];
#pragma unroll
    for (int tt = 0; tt < 4; ++tt)
#pragma unroll
        for (int nt = 0; nt < 8; ++nt) acc[tt][nt] = (f32x4){0.f, 0.f, 0.f, 0.f};

#pragma unroll
    for (int kt = 0; kt < 8; ++kt) {
        bf16x8 af[4];
#pragma unroll
        for (int tt = 0; tt < 4; ++tt)
            af[tt] = *(const bf16x8*)&At[(tt * 16 + l16) * LDH + kt * 32 + quad * 8];
#pragma unroll
        for (int nt = 0; nt < 8; ++nt) {
            bf16x8 wf = *(const bf16x8*)&WxF[(((size_t)(wv * 8 + nt) * 8 + kt) * 64 + lane) * 8];
#pragma unroll
            for (int tt = 0; tt < 4; ++tt) acc[tt][nt] = mfma16(af[tt], wf, acc[tt][nt]);
        }
    }

    // epilogue: +bias (+forget), fp16, swizzled write (4 r-values = one 8B store)
#pragma unroll
    for (int nt = 0; nt < 8; ++nt) {
        int col = wv * 128 + nt * 16 + l16;
        float bb = bias[col] + ((col >= 512 && col < 768) ? 1.0f : 0.0f);
#pragma unroll
        for (int tt = 0; tt < 4; ++tt) {
            int t = tg * 4 + tt;
            union { __half h[4]; uint2 u; } pk;
#pragma unroll
            for (int r = 0; r < 4; ++r) pk.h[r] = __float2half(acc[tt][nt][r] + bb);
            *(uint2*)(Zx + ((((size_t)(rb * 128 + t) * 8 + nt) * 64 + lane) * 32 + wv * 4)) = pk.u;
        }
    }
}

// ---------------- 3) recurrent loop ----------------
__global__ __launch_bounds__(512, 2) void lstm_rec(const __bf16* __restrict__ WhF,
        const __half* __restrict__ Zx, const float* __restrict__ wout,
        const float* __restrict__ bout, float* __restrict__ out) {
    extern __shared__ char smem[];
    __bf16* fragL = (__bf16*)smem;               // [wv][NLDSF][lane][8]
    __bf16* Ht    = (__bf16*)(smem + HT_OFF);    // [16][LDH]
    const int tid = threadIdx.x, wv = tid >> 6, lane = tid & 63;
    const int l16 = lane & 15, quad = lane >> 4;
    const int rb = blockIdx.x;

    // load Wh frags: n-tile n (g=n>>1, half=n&1): col = g*256+half*128+wv*16+l16
    bf16x8 wreg[NREGF];
#pragma unroll
    for (int kt = 0; kt < 8; ++kt)
#pragma unroll
        for (int n = 0; n < 8; ++n) {
            int f = kt * 8 + n;
            int ng = (n >> 1) * 16 + (n & 1) * 8 + wv;
            bf16x8 v = *(const bf16x8*)&WhF[((size_t)(ng * 8 + kt) * 64 + lane) * 8];
            if (f < NREGF) wreg[f] = v;
            else *(bf16x8*)&fragL[((size_t)(wv * NLDSF + (f - NREGF)) * 64 + lane) * 8] = v;
        }

    for (int i = tid; i < 16 * LDH; i += 512) Ht[i] = (__bf16)0.0f;
    float c_[2][4] = {{0.f,0.f,0.f,0.f},{0.f,0.f,0.f,0.f}};
    __syncthreads();

    const __half* zbase = Zx + (((size_t)rb * 128 * 8 + wv) * 64 + lane) * 32;

#pragma unroll 1
    for (int t = 0; t < 128; ++t) {
        // this lane's 32 z-values: contiguous 64 B (latency hidden behind MFMA)
        union { uint4 q[4]; uint u[16]; } z;
        {
            const uint4* zp = (const uint4*)(zbase + (size_t)t * 16384);
            z.q[0] = zp[0]; z.q[1] = zp[1]; z.q[2] = zp[2]; z.q[3] = zp[3];
        }
        f32x4 acc[8];
#pragma unroll
        for (int n = 0; n < 8; ++n) acc[n] = (f32x4){0.f, 0.f, 0.f, 0.f};
#pragma unroll
        for (int kt = 0; kt < 8; ++kt) {
            bf16x8 af = *(const bf16x8*)&Ht[l16 * LDH + kt * 32 + quad * 8];
#pragma unroll
            for (int n = 0; n < 8; ++n) {
                int f = kt * 8 + n;
                bf16x8 wf;
                if (f < NREGF) wf = wreg[f];
                else wf = *(const bf16x8*)&fragL[((size_t)(wv * NLDSF + (f - NREGF)) * 64 + lane) * 8];
                acc[n] = mfma16(af, wf, acc[n]);
            }
        }
        __syncthreads();   // all Ht reads done before rewrite

        // epilogue: z-idx for (g,half,r) = (g*2+half)*4+r (compile-time)
#pragma unroll
        for (int hf = 0; hf < 2; ++hf) {
            int cc = hf * 128 + wv * 16 + l16;
#pragma unroll
            for (int r = 0; r < 4; ++r) {
#define ZGET(ix) __half2float(((ix) & 1) ? ((__half2*)&z.u[(ix) >> 1])->y : ((__half2*)&z.u[(ix) >> 1])->x)
                float iv = acc[0 + hf][r] + ZGET((0 * 2 + hf) * 4 + r);
                float jv = acc[2 + hf][r] + ZGET((1 * 2 + hf) * 4 + r);
                float fv = acc[4 + hf][r] + ZGET((2 * 2 + hf) * 4 + r);
                float ov = acc[6 + hf][r] + ZGET((3 * 2 + hf) * 4 + r);
#undef ZGET
                float c = c_[hf][r] * sig_(fv) + sig_(iv) * th_(jv);
                c_[hf][r] = c;
                Ht[(quad * 4 + r) * LDH + cc] = (__bf16)(th_(c) * sig_(ov));
            }
        }
        __syncthreads();   // Ht(t+1) ready
    }

    // output projection: out[16,128] = h_last @ wout + bout (all 8 waves, 16 cols each)
    bf16x8 wo[8];
#pragma unroll
    for (int kt = 0; kt < 8; ++kt) {
        bf16x8 f;
#pragma unroll
        for (int j = 0; j < 8; ++j)
            f[j] = (__bf16)wout[(size_t)(kt * 32 + quad * 8 + j) * 128 + wv * 16 + l16];
        wo[kt] = f;
    }
    f32x4 oa = {0.f, 0.f, 0.f, 0.f};
#pragma unroll
    for (int kt = 0; kt < 8; ++kt) {
        bf16x8 af = *(const bf16x8*)&Ht[l16 * LDH + kt * 32 + quad * 8];
        oa = mfma16(af, wo[kt], oa);
    }
    float bo = bout[wv * 16 + l16];
#pragma unroll
    for (int r = 0; r < 4; ++r)
        out[(size_t)(rb * 16 + quad * 4 + r) * 128 + wv * 16 + l16] = oa[r] + bo;
}

extern "C" void kernel_launch(void* const* d_in, const int* in_sizes, int n_in,
                              void* d_out, int out_size, void* d_ws, size_t ws_size,
                              hipStream_t stream) {
    const float* x    = (const float*)d_in[0];
    const float* Wk   = (const float*)d_in[1];
    const float* bias = (const float*)d_in[2];
    const float* wout = (const float*)d_in[3];
    const float* bout = (const float*)d_in[4];
    float* out = (float*)d_out;

    __bf16* WF  = (__bf16*)d_ws;                         // WxF [0,262144), WhF [262144,524288) elems
    __half* Zx  = (__half*)((char*)d_ws + 1048576);      // 134,217,728 B

    // allow >64 KiB dynamic LDS (attribute set, not a stream op; idempotent)
    hipFuncSetAttribute((const void*)lstm_rec,
                        hipFuncAttributeMaxDynamicSharedMemorySize, SMEM_BYTES);

    shuffle_w<<<256, 256, 0, stream>>>(Wk, WF);
    xproj<<<1024, 512, 0, stream>>>(x, WF, bias, Zx);
    lstm_rec<<<32, 512, SMEM_BYTES, stream>>>(WF + 262144, Zx, wout, bout, out);
}

// Round 3
// 593.423 us; speedup vs baseline: 5.0256x; 1.4199x over previous
//
#include <hip/hip_runtime.h>
#include <hip/hip_fp16.h>
#include <stdint.h>
#include <stddef.h>

// LSTM B=512,T=128,D=256,H=256,C=128, gates (i,j,f,o), FORGET_BIAS=1.
//  1) shuffle_w : Wk -> bf16 B-frags (Wx) + fp8-e4m3 B-frags (Wh) in ws
//  2) xproj     : Zx = x@Wx + bias(+1 on f), fp16 swizzled records,
//                 LDS-transposed so global writes are fully coalesced
//  3) lstm_rec  : 32 blocks x 512 thr; Wh fp8 100% register-resident
//                 (64 frags x 8B = 128 VGPR/wave), Ht fp8 in LDS, c fp32 regs

typedef __attribute__((ext_vector_type(8))) __bf16 bf16x8;
typedef __attribute__((ext_vector_type(4))) __bf16 bf16x4;
typedef __attribute__((ext_vector_type(4))) float  f32x4;

#define LDH   264     // At row stride (bf16 elems) in xproj; HtB stride in rec
#define LDH8  264     // Ht row stride in BYTES (fp8) in rec

__device__ __forceinline__ f32x4 mfma_bf16(bf16x8 a, bf16x8 b, f32x4 c) {
    return __builtin_amdgcn_mfma_f32_16x16x32_bf16(a, b, c, 0, 0, 0);
}
__device__ __forceinline__ f32x4 mfma_fp8(long a, long b, f32x4 c) {
    return __builtin_amdgcn_mfma_f32_16x16x32_fp8_fp8(a, b, c, 0, 0, 0);
}
__device__ __forceinline__ float clamp30(float x) { return fminf(fmaxf(x, -30.f), 30.f); }
#define EXP2(x) __builtin_amdgcn_exp2f(x)
#define RCP(x)  __builtin_amdgcn_rcpf(x)
#define L2E  1.442695040f
#define L2E2 2.885390082f

// ---------------- 1) weight shuffle ----------------
__global__ __launch_bounds__(256) void shuffle_w(const float* __restrict__ Wk,
                                                 __bf16* __restrict__ WxF,
                                                 unsigned char* __restrict__ WhF) {
    int id = blockIdx.x * 256 + threadIdx.x;          // 0..65535
    int part = id >> 15;                              // 0 = Wx (bf16), 1 = Wh (fp8)
    int i = id & 32767;
    int lane = i & 63, kt = (i >> 6) & 7, nt = i >> 9;
    int quad = lane >> 4, l16 = lane & 15;
    const float* src = Wk + (size_t)(part * 256 + kt * 32 + quad * 8) * 1024 + nt * 16 + l16;
    float w[8];
#pragma unroll
    for (int j = 0; j < 8; ++j) w[j] = src[(size_t)j * 1024];
    if (part == 0) {
        __bf16* dst = WxF + ((size_t)(nt * 8 + kt) * 64 + lane) * 8;
#pragma unroll
        for (int j = 0; j < 8; ++j) dst[j] = (__bf16)w[j];
    } else {
        int a = __builtin_amdgcn_cvt_pk_fp8_f32(w[0], w[1], 0, false);
        a     = __builtin_amdgcn_cvt_pk_fp8_f32(w[2], w[3], a, true);
        int b = __builtin_amdgcn_cvt_pk_fp8_f32(w[4], w[5], 0, false);
        b     = __builtin_amdgcn_cvt_pk_fp8_f32(w[6], w[7], b, true);
        int2 v = {a, b};
        *(int2*)(WhF + ((size_t)(nt * 8 + kt) * 64 + lane) * 8) = v;
    }
}

// ---------------- 2) x-projection ----------------
// Zx record layout (fp16): ((rb*128+t)*8 + cw)*64 + lane)*32 + (g*2+hf)*4 + r
__global__ __launch_bounds__(512, 2) void xproj(const float* __restrict__ x,
        const __bf16* __restrict__ WxF, const float* __restrict__ bias,
        __half* __restrict__ Zx) {
    __shared__ __attribute__((aligned(16))) char smem[64 * LDH * 2];  // At / Lz union
    __bf16* At = (__bf16*)smem;
    const int tid = threadIdx.x, wv = tid >> 6, lane = tid & 63;
    const int l16 = lane & 15, quad = lane >> 4;
    const int rb = blockIdx.x & 31, tg = blockIdx.x >> 5;

    // stage A: 64 rows = 16 b-rows x 4 t (coalesced float4)
#pragma unroll
    for (int rr = 0; rr < 8; ++rr) {
        int Arow = wv * 8 + rr;
        int tt = Arow >> 4, r = Arow & 15;
        const float4 xv = *((const float4*)(x + ((size_t)(rb * 16 + r) * 128 + tg * 4 + tt) * 256) + lane);
        bf16x4 xb = { (__bf16)xv.x, (__bf16)xv.y, (__bf16)xv.z, (__bf16)xv.w };
        *(bf16x4*)&At[Arow * LDH + lane * 4] = xb;
    }
    __syncthreads();

    f32x4 acc[4][8];
#pragma unroll
    for (int tt = 0; tt < 4; ++tt)
#pragma unroll
        for (int nt = 0; nt < 8; ++nt) acc[tt][nt] = (f32x4){0.f, 0.f, 0.f, 0.f};

#pragma unroll
    for (int kt = 0; kt < 8; ++kt) {
        bf16x8 af[4];
#pragma unroll
        for (int tt = 0; tt < 4; ++tt)
            af[tt] = *(const bf16x8*)&At[(tt * 16 + l16) * LDH + kt * 32 + quad * 8];
#pragma unroll
        for (int nt = 0; nt < 8; ++nt) {
            bf16x8 wf = *(const bf16x8*)&WxF[(((size_t)(wv * 8 + nt) * 8 + kt) * 64 + lane) * 8];
#pragma unroll
            for (int tt = 0; tt < 4; ++tt) acc[tt][nt] = mfma_bf16(af[tt], wf, acc[tt][nt]);
        }
    }

    float bb[8];
#pragma unroll
    for (int nt = 0; nt < 8; ++nt) {
        int col = wv * 128 + nt * 16 + l16;
        bb[nt] = bias[col] + ((col >= 512 && col < 768) ? 1.0f : 0.0f);
    }

    // epilogue: LDS transpose per tt, then coalesced 32KB stream
    uint2* Lz2 = (uint2*)smem;
    const uint4* Ls = (const uint4*)smem;
#pragma unroll 1
    for (int tt = 0; tt < 4; ++tt) {
        __syncthreads();   // At reads (tt=0) / prior stream (tt>0) complete
#pragma unroll
        for (int nt = 0; nt < 8; ++nt) {
            union { __half h[4]; uint2 u; } pk;
#pragma unroll
            for (int r = 0; r < 4; ++r) pk.h[r] = __float2half(acc[tt][nt][r] + bb[nt]);
            Lz2[(((wv >> 1) * 8 + nt) * 64 + lane) * 2 + (wv & 1)] = pk.u;
        }
        __syncthreads();
        int t = tg * 4 + tt;
        uint4* dst = (uint4*)Zx + (size_t)(rb * 128 + t) * 2048;
#pragma unroll
        for (int k = 0; k < 4; ++k) {
            int e = k * 512 + tid;                  // output uint4 index (coalesced)
            int wp = e & 3, ln = (e >> 2) & 63, nt2 = (e >> 8) & 7;
            dst[e] = Ls[(wp * 8 + nt2) * 64 + ln];
        }
    }
}

// ---------------- 3) recurrent loop ----------------
__global__ __launch_bounds__(512, 2) void lstm_rec(const long* __restrict__ WhF,
        const __half* __restrict__ Zx, const float* __restrict__ wout,
        const float* __restrict__ bout, float* __restrict__ out) {
    __shared__ __attribute__((aligned(16))) unsigned char Ht[16 * LDH8];  // fp8 h
    __shared__ __attribute__((aligned(16))) __bf16 HtB[16 * LDH];         // bf16 h (final)
    const int tid = threadIdx.x, wv = tid >> 6, lane = tid & 63;
    const int l16 = lane & 15, quad = lane >> 4;
    const int rb = blockIdx.x;

    // Wh fp8 B-frags, fully register-resident: 64 x 8B = 128 VGPR
    long wreg[64];
#pragma unroll
    for (int n = 0; n < 8; ++n) {
        int ng = (n >> 1) * 16 + (n & 1) * 8 + wv;   // cols g*256+hf*128+wv*16+l16
#pragma unroll
        for (int kt = 0; kt < 8; ++kt)
            wreg[kt * 8 + n] = WhF[(size_t)(ng * 8 + kt) * 64 + lane];
    }
    for (int i = tid; i < 16 * LDH8; i += 512) Ht[i] = 0;
    float c_[2][4] = {{0.f,0.f,0.f,0.f},{0.f,0.f,0.f,0.f}};
    float hr[2][4] = {{0.f,0.f,0.f,0.f},{0.f,0.f,0.f,0.f}};
    __syncthreads();

    const __half* zbase = Zx + (((size_t)rb * 1024 + wv) * 64 + lane) * 32;

#pragma unroll 1
    for (int t = 0; t < 128; ++t) {
        // this lane's 32 z-values: contiguous 64B (issued early, hidden by MFMA)
        union { uint4 q[4]; unsigned u[16]; } z;
        {
            const uint4* zp = (const uint4*)(zbase + (size_t)t * 16384);
            z.q[0] = zp[0]; z.q[1] = zp[1]; z.q[2] = zp[2]; z.q[3] = zp[3];
        }
        long af[8];
#pragma unroll
        for (int kt = 0; kt < 8; ++kt)
            af[kt] = *(const long*)&Ht[l16 * LDH8 + kt * 32 + quad * 8];
        __syncthreads();   // WAR: all waves hold Ht(t) in regs

        f32x4 acc[8];
#pragma unroll
        for (int n = 0; n < 8; ++n) acc[n] = (f32x4){0.f, 0.f, 0.f, 0.f};
#pragma unroll
        for (int kt = 0; kt < 8; ++kt)
#pragma unroll
            for (int n = 0; n < 8; ++n)
                acc[n] = mfma_fp8(af[kt], wreg[kt * 8 + n], acc[n]);

        // epilogue: shared-denominator gate algebra (5 exp2 + 2 rcp per h)
#pragma unroll
        for (int hf = 0; hf < 2; ++hf) {
#pragma unroll
            for (int r = 0; r < 4; ++r) {
#define ZGET(ix) __half2float(((ix) & 1) ? ((__half2*)&z.u[(ix) >> 1])->y : ((__half2*)&z.u[(ix) >> 1])->x)
                float iv = acc[0 + hf][r] + ZGET((0 * 2 + hf) * 4 + r);
                float jv = acc[2 + hf][r] + ZGET((1 * 2 + hf) * 4 + r);
                float fv = acc[4 + hf][r] + ZGET((2 * 2 + hf) * 4 + r);
                float ov = acc[6 + hf][r] + ZGET((3 * 2 + hf) * 4 + r);
#undef ZGET
                float Ei = EXP2(clamp30(-L2E  * iv));
                float Ef = EXP2(clamp30(-L2E  * fv));
                float G  = EXP2(clamp30(-L2E2 * jv));
                float pI = 1.f + Ei, pF = 1.f + Ef, pG = 1.f + G, mG = 1.f - G;
                float t1 = pI * pG;
                float cn = (c_[hf][r] * t1 + pF * mG) * RCP(pF * t1);
                c_[hf][r] = cn;
                float Ec = EXP2(clamp30(-L2E2 * cn));
                float Eo = EXP2(clamp30(-L2E  * ov));
                float h  = (1.f - Ec) * RCP((1.f + Ec) * (1.f + Eo));
                hr[hf][r] = h;
                unsigned pb = (unsigned)__builtin_amdgcn_cvt_pk_fp8_f32(h, h, 0, false);
                Ht[(quad * 4 + r) * LDH8 + hf * 128 + wv * 16 + l16] = (unsigned char)pb;
            }
        }
        __syncthreads();   // RAW: Ht(t+1) visible
    }

    // ---- output projection in bf16 (no fp8 error on the last matmul) ----
#pragma unroll
    for (int hf = 0; hf < 2; ++hf)
#pragma unroll
        for (int r = 0; r < 4; ++r)
            HtB[(quad * 4 + r) * LDH + hf * 128 + wv * 16 + l16] = (__bf16)hr[hf][r];
    __syncthreads();

    if (wv < 8) {
        bf16x8 wo[8];
#pragma unroll
        for (int kt = 0; kt < 8; ++kt) {
            bf16x8 f;
#pragma unroll
            for (int j = 0; j < 8; ++j)
                f[j] = (__bf16)wout[(size_t)(kt * 32 + quad * 8 + j) * 128 + wv * 16 + l16];
            wo[kt] = f;
        }
        f32x4 oa = {0.f, 0.f, 0.f, 0.f};
#pragma unroll
        for (int kt = 0; kt < 8; ++kt) {
            bf16x8 af = *(const bf16x8*)&HtB[l16 * LDH + kt * 32 + quad * 8];
            oa = mfma_bf16(af, wo[kt], oa);
        }
        float bo = bout[wv * 16 + l16];
#pragma unroll
        for (int r = 0; r < 4; ++r)
            out[(size_t)(rb * 16 + quad * 4 + r) * 128 + wv * 16 + l16] = oa[r] + bo;
    }
}

extern "C" void kernel_launch(void* const* d_in, const int* in_sizes, int n_in,
                              void* d_out, int out_size, void* d_ws, size_t ws_size,
                              hipStream_t stream) {
    const float* x    = (const float*)d_in[0];
    const float* Wk   = (const float*)d_in[1];
    const float* bias = (const float*)d_in[2];
    const float* wout = (const float*)d_in[3];
    const float* bout = (const float*)d_in[4];
    float* out = (float*)d_out;

    __bf16*        WxF = (__bf16*)d_ws;                         // 512 KB
    unsigned char* WhF = (unsigned char*)d_ws + 524288;         // 256 KB fp8
    __half*        Zx  = (__half*)((char*)d_ws + 1048576);      // 128 MB

    shuffle_w<<<256, 256, 0, stream>>>(Wk, WxF, WhF);
    xproj<<<1024, 512, 0, stream>>>(x, WxF, bias, Zx);
    lstm_rec<<<32, 512, 0, stream>>>((const long*)WhF, Zx, wout, bout, out);
}